// Round 5
// baseline (486.274 us; speedup 1.0000x reference)
//
#include <hip/hip_runtime.h>

// Caps_Layer: x[1024,512,120] f32, W[120,25] f32 -> out[1024,5,5] f32
// Round 6: register-streaming GEMM, no LDS x-tile, no GEMM barriers.
// Post-mortem of rounds 0/3/4/5: four different LDS stagings all ~170-197us
// with VALU 19% / HBM 22% / occ 22% -- latency-bound on the barrier-
// serialized stage->compute cycle with only ~2 blocks/CU of TLP, plus 1.44x
// fetch inflation (48B tile chunks straddling 128B lines). Also
// SQ_LDS_BANK_CONFLICT stayed 4.0M with ZERO ds_writes in round 5 -> the
// conflicts are the routing shfl butterfly, not GEMM staging.
// New structure: 512 threads/block, 1 row/thread, stream the full 480B row
// into 30 float4 registers (30 outstanding loads/wave x 8 waves of MLP),
// FMA against scalar-loaded W. Dense wave-level fetch (64 adjacent rows =
// contiguous 30KB region) -> every line fetched once. LDS = 800B (red only).
// Lesson kept: no min-waves launch-bounds hint (round-2 spill disaster).

#define NCAP 5
#define DCAP 5
#define NOUT 25      // NCAP*DCAP
#define DIN 120
#define SEQ 512
#define ROUTINGS 4
#define NQ   30      // float4 quads per row (120/4)

__global__ __launch_bounds__(512) void caps_kernel(
    const float* __restrict__ x,   // [batch, 512, 120]
    const float* __restrict__ W,   // [120, 25]
    float* __restrict__ out)       // [batch, 5, 5]
{
    const int b    = blockIdx.x;
    const int t    = threadIdx.x;   // 0..511 == row index
    const int lane = t & 63;
    const int wv   = t >> 6;        // 0..7

    __shared__ float red[8][NOUT];  // 800 B

    const float* xr = x + (size_t)b * SEQ * DIN + (size_t)t * DIN;

    // ---------- GEMM phase: stream full row to registers, zero barriers ----
    float4 rv[NQ];                  // 120 VGPRs, all 30 loads in flight
#pragma unroll
    for (int q = 0; q < NQ; ++q)
        rv[q] = *(const float4*)(xr + 4 * q);

    float acc[NOUT];
#pragma unroll
    for (int j = 0; j < NOUT; ++j) acc[j] = 0.f;

#pragma unroll
    for (int q = 0; q < NQ; ++q) {
        const float* wr = W + (4 * q) * NOUT;   // wave-uniform -> s_load
#pragma unroll
        for (int j = 0; j < NOUT; ++j) {
            float w0 = wr[j];
            float w1 = wr[j + NOUT];
            float w2 = wr[j + 2 * NOUT];
            float w3 = wr[j + 3 * NOUT];
            acc[j] = fmaf(rv[q].w, w3,
                     fmaf(rv[q].z, w2,
                     fmaf(rv[q].y, w1,
                     fmaf(rv[q].x, w0, acc[j]))));
        }
    }

    // ---------- Routing phase (1 row per thread) ----------
    float bb[NCAP];
#pragma unroll
    for (int c = 0; c < NCAP; ++c) bb[c] = 0.f;

    float o[NOUT];

    for (int it = 0; it < ROUTINGS; ++it) {
        // softmax over capsule axis for this row
        float m = bb[0];
#pragma unroll
        for (int c = 1; c < NCAP; ++c) m = fmaxf(m, bb[c]);
        float e[NCAP]; float se = 0.f;
#pragma unroll
        for (int c = 0; c < NCAP; ++c) { e[c] = __expf(bb[c] - m); se += e[c]; }
        float inv = 1.f / se;

        float p[NOUT];
#pragma unroll
        for (int c = 0; c < NCAP; ++c) {
            float cc = e[c] * inv;
#pragma unroll
            for (int k = 0; k < DCAP; ++k)
                p[c*DCAP + k] = cc * acc[c*DCAP + k];
        }

        // block reduction over 512 rows: 64-lane butterfly, then 8 waves via LDS
#pragma unroll
        for (int d = 1; d < 64; d <<= 1)
#pragma unroll
            for (int j = 0; j < NOUT; ++j) p[j] += __shfl_xor(p[j], d, 64);

        if (lane == 0) {
#pragma unroll
            for (int j = 0; j < NOUT; ++j) red[wv][j] = p[j];
        }
        __syncthreads();
        float s[NOUT];
#pragma unroll
        for (int j = 0; j < NOUT; ++j)
            s[j] = red[0][j] + red[1][j] + red[2][j] + red[3][j]
                 + red[4][j] + red[5][j] + red[6][j] + red[7][j];
        __syncthreads();

        // squash per capsule
#pragma unroll
        for (int c = 0; c < NCAP; ++c) {
            float ss = 0.f;
#pragma unroll
            for (int k = 0; k < DCAP; ++k)
                ss = fmaf(s[c*DCAP + k], s[c*DCAP + k], ss);
            float sc = rsqrtf(ss + 1e-7f);
#pragma unroll
            for (int k = 0; k < DCAP; ++k) o[c*DCAP + k] = s[c*DCAP + k] * sc;
        }

        if (it < ROUTINGS - 1) {
#pragma unroll
            for (int c = 0; c < NCAP; ++c) {
                float d0 = 0.f;
#pragma unroll
                for (int k = 0; k < DCAP; ++k)
                    d0 = fmaf(o[c*DCAP + k], acc[c*DCAP + k], d0);
                bb[c] = d0;
            }
        }
    }

    if (t < NOUT) out[(size_t)b * NOUT + t] = o[t];
}

extern "C" void kernel_launch(void* const* d_in, const int* in_sizes, int n_in,
                              void* d_out, int out_size, void* d_ws, size_t ws_size,
                              hipStream_t stream) {
    const float* x   = (const float*)d_in[0];
    const float* W   = (const float*)d_in[1];
    float*       o   = (float*)d_out;
    const int batch  = in_sizes[0] / (SEQ * DIN);   // 1024
    caps_kernel<<<dim3(batch), dim3(512), 0, stream>>>(x, W, o);
}

// Round 6
// 465.595 us; speedup vs baseline: 1.0444x; 1.0444x over previous
//
#include <hip/hip_runtime.h>

// Caps_Layer: x[1024,512,120] f32, W[120,25] f32 -> out[1024,5,5] f32
// Round 7: TWO-KERNEL SPLIT.
// Evidence from rounds 0-5: (a) L3-resident replays (FETCH 0.13MB) run the
// SAME ~190-250us as cold ones -> pure latency-bound, not BW; (b) bank
// conflicts were GEMM ds_reads, not the shfl butterfly (round 5: 0 with
// butterfly present); (c) grid=1024 (4 blocks/CU) + per-block serialization
// means latency is never hidden, regardless of staging scheme.
// The block-per-batch shape is only forced by routing's cross-row reduce.
// So: K1 = pure streaming GEMM u_hat = x@W at 8 blocks/CU, zero barriers,
// output transposed [b][25][512]; K2 = routing on 52MB (not 251MB), block
// per batch, 2 rows/thread (halves butterfly DS-pipe cost vs round 5).
// Extra traffic: +52MB write +52MB read (~17us) for 4-8x latency hiding.

#define NCAP 5
#define DCAP 5
#define NOUT 25      // NCAP*DCAP
#define DIN 120
#define SEQ 512
#define ROUTINGS 4

// ---------------- K1: u_hat GEMM, transposed store ----------------
// grid = batch*2 blocks x 256 threads, 1 row per thread.
// Chunked streaming (6 chunks x 5 float4) with unroll 1 keeps VGPR low
// (target <=64 -> 8 waves/SIMD) while 5x64-line requests/chunk/wave x
// 24+ waves/CU give ample MLP. W via wave-uniform s_loads (12KB, cached).
__global__ __launch_bounds__(256) void gemm_kernel(
    const float* __restrict__ x,   // [batch, 512, 120]
    const float* __restrict__ W,   // [120, 25]
    float* __restrict__ uh)        // [batch, 25, 512]
{
    const int gid = blockIdx.x * 256 + threadIdx.x;   // global row
    const int b   = gid >> 9;          // gid / 512
    const int r   = gid & 511;
    const float* xr = x + (size_t)gid * DIN;

    float acc[NOUT];
#pragma unroll
    for (int j = 0; j < NOUT; ++j) acc[j] = 0.f;

#pragma unroll 1
    for (int ch = 0; ch < 6; ++ch) {
        float4 v[5];
#pragma unroll
        for (int u = 0; u < 5; ++u)
            v[u] = *(const float4*)(xr + ch * 20 + 4 * u);
#pragma unroll
        for (int u = 0; u < 5; ++u) {
            const float* wr = W + (ch * 20 + 4 * u) * NOUT;  // uniform -> s_load
#pragma unroll
            for (int j = 0; j < NOUT; ++j) {
                float w0 = wr[j];
                float w1 = wr[j + NOUT];
                float w2 = wr[j + 2 * NOUT];
                float w3 = wr[j + 3 * NOUT];
                acc[j] = fmaf(v[u].w, w3,
                         fmaf(v[u].z, w2,
                         fmaf(v[u].y, w1,
                         fmaf(v[u].x, w0, acc[j]))));
            }
        }
    }

    // transposed store: lanes (=rows) contiguous per j -> coalesced
    float* ub = uh + (size_t)b * NOUT * SEQ + r;
#pragma unroll
    for (int j = 0; j < NOUT; ++j) ub[(size_t)j * SEQ] = acc[j];
}

// ---------------- K2: dynamic routing ----------------
// grid = batch blocks x 256 threads, rows t and t+256 per thread.
// u loads are perfectly coalesced (lane-stride-4B per j). p merged over
// the thread's 2 rows in VALU before the 64-lane butterfly -> half the
// DS-pipe traffic of the 512-thread version.
__global__ __launch_bounds__(256) void route_kernel(
    const float* __restrict__ uh,  // [batch, 25, 512]
    float* __restrict__ out)       // [batch, 5, 5]
{
    const int b    = blockIdx.x;
    const int t    = threadIdx.x;
    const int lane = t & 63;
    const int wv   = t >> 6;

    __shared__ float red[4][NOUT];

    const float* ub = uh + (size_t)b * NOUT * SEQ;
    float u0[NOUT], u1[NOUT];
#pragma unroll
    for (int j = 0; j < NOUT; ++j) {
        u0[j] = ub[(size_t)j * SEQ + t];
        u1[j] = ub[(size_t)j * SEQ + t + 256];
    }

    float bb0[NCAP], bb1[NCAP];
#pragma unroll
    for (int c = 0; c < NCAP; ++c) { bb0[c] = 0.f; bb1[c] = 0.f; }

    float s[NOUT], sc[NCAP];

    for (int it = 0; it < ROUTINGS; ++it) {
        // per-row softmax over capsules
        float m0 = bb0[0], m1 = bb1[0];
#pragma unroll
        for (int c = 1; c < NCAP; ++c) { m0 = fmaxf(m0, bb0[c]); m1 = fmaxf(m1, bb1[c]); }
        float e0[NCAP], e1[NCAP]; float se0 = 0.f, se1 = 0.f;
#pragma unroll
        for (int c = 0; c < NCAP; ++c) {
            e0[c] = __expf(bb0[c] - m0); se0 += e0[c];
            e1[c] = __expf(bb1[c] - m1); se1 += e1[c];
        }
        float i0 = 1.f / se0, i1 = 1.f / se1;

        float p[NOUT];
#pragma unroll
        for (int c = 0; c < NCAP; ++c) {
            float c0 = e0[c] * i0, c1 = e1[c] * i1;
#pragma unroll
            for (int k = 0; k < DCAP; ++k)
                p[c*DCAP + k] = fmaf(c0, u0[c*DCAP + k], c1 * u1[c*DCAP + k]);
        }

        // 64-lane butterfly, then 4 waves via LDS
#pragma unroll
        for (int d = 1; d < 64; d <<= 1)
#pragma unroll
            for (int j = 0; j < NOUT; ++j) p[j] += __shfl_xor(p[j], d, 64);

        if (lane == 0) {
#pragma unroll
            for (int j = 0; j < NOUT; ++j) red[wv][j] = p[j];
        }
        __syncthreads();
#pragma unroll
        for (int j = 0; j < NOUT; ++j)
            s[j] = red[0][j] + red[1][j] + red[2][j] + red[3][j];
        __syncthreads();

        // squash scale per capsule
#pragma unroll
        for (int c = 0; c < NCAP; ++c) {
            float ss = 0.f;
#pragma unroll
            for (int k = 0; k < DCAP; ++k)
                ss = fmaf(s[c*DCAP + k], s[c*DCAP + k], ss);
            sc[c] = rsqrtf(ss + 1e-7f);
        }

        if (it < ROUTINGS - 1) {
#pragma unroll
            for (int c = 0; c < NCAP; ++c) {
                float d0 = 0.f, d1 = 0.f;
#pragma unroll
                for (int k = 0; k < DCAP; ++k) {
                    float oc = s[c*DCAP + k] * sc[c];
                    d0 = fmaf(oc, u0[c*DCAP + k], d0);
                    d1 = fmaf(oc, u1[c*DCAP + k], d1);
                }
                bb0[c] = d0; bb1[c] = d1;
            }
        }
    }

    if (t < NOUT) out[(size_t)b * NOUT + t] = s[t] * sc[t / DCAP];
}

extern "C" void kernel_launch(void* const* d_in, const int* in_sizes, int n_in,
                              void* d_out, int out_size, void* d_ws, size_t ws_size,
                              hipStream_t stream) {
    const float* x   = (const float*)d_in[0];
    const float* W   = (const float*)d_in[1];
    float*       o   = (float*)d_out;
    float*       uh  = (float*)d_ws;                 // batch*25*512*4 = 52.4 MB
    const int batch  = in_sizes[0] / (SEQ * DIN);    // 1024

    gemm_kernel<<<dim3(batch * 2), dim3(256), 0, stream>>>(x, W, uh);
    route_kernel<<<dim3(batch),    dim3(256), 0, stream>>>(uh, o);
}

// Round 7
// 421.217 us; speedup vs baseline: 1.1544x; 1.1054x over previous
//
#include <hip/hip_runtime.h>

// Caps_Layer: x[1024,512,120] f32, W[120,25] f32 -> out[1024,5,5] f32
// Round 8: split kept; K1 rebuilt as the (proven) round-4 LDS async pipeline
// at 2x grid.
// Post-mortem r6: K1's VGPR_Count=28 with 25 live accumulators => my
// "#pragma unroll 1" made the allocator SPILL acc[] to scratch; spill live
// set (~120KB/CU) is L2-resident so it never showed in FETCH/WRITE -- this
// is why register-streaming variants were insensitive to data residency.
// Also 480B-stride lane access inflated FETCH 1.87x (439MB). Both fixed by
// returning to coalesced global_load_lds staging (round 4: zero conflicts,
// zero spill at VGPR 100) with HALF the rows per block and 2x the blocks:
//   K1: 2048 blocks x 256 thr, 256 rows/block, 1 row/thread, KT=12,
//       double-buffered 2x12.3KB LDS -> ~6 resident blocks/CU (vs 2.8 in
//       r4) so cross-block TLP covers the per-tile barrier drain.
//   K2: unchanged (measured ~46us).
// Lessons enforced: no launch_bounds min-waves hint, no unroll-1, acc must
// stay in VGPRs (abort-signal: VGPR>=90 or WRITE_SIZE>52MB).

#define NCAP 5
#define DCAP 5
#define NOUT 25      // NCAP*DCAP
#define DIN 120
#define SEQ 512
#define ROUTINGS 4

#define KT    12     // K-tile (120 = 10*12); 48B row stride -> b128 conflict-free
#define NTILE 10
#define RPB   256    // rows per block
#define BUFF  (RPB * KT)   // 3072 floats = 12,288 B per buffer

typedef __attribute__((address_space(3))) void        as3_void;
typedef const __attribute__((address_space(1))) void  as1_void;

// ---------------- K1: u_hat GEMM, LDS-staged, transposed store ----------
__global__ __launch_bounds__(256) void gemm_kernel(
    const float* __restrict__ x,   // [batch, 512, 120]
    const float* __restrict__ W,   // [120, 25]
    float* __restrict__ uh)        // [batch, 25, 512]
{
    const int blk  = blockIdx.x;        // 0..2*batch-1
    const int b    = blk >> 1;
    const int half = blk & 1;
    const int t    = threadIdx.x;       // 0..255 == local row
    const int wv   = t >> 6;

    __shared__ float xt[2][BUFF];       // 24,576 B double buffer, [row][12]

    const float* xb = x + ((size_t)b * SEQ + half * RPB) * DIN;

    // async stage of one K-tile: 768 float4 chunks, 3/thread.
    // slot f = t + 256*i <-> (row = f/3, quad = f%3); lanes cover 48B
    // contiguous runs (coalesced); LDS dest wave-uniform (HW adds lane*16).
    auto stage = [&](int bufi, int tile) {
        const int k0 = tile * KT;
#pragma unroll
        for (int i = 0; i < 3; ++i) {
            unsigned f   = (unsigned)t + 256u * (unsigned)i;
            unsigned row = f / 3u;
            unsigned q   = f - row * 3u;
            const float* gsrc = xb + row * DIN + k0 + 4u * q;
            float*      ldst = &xt[bufi][1024 * i + 256 * wv];   // float offset
            __builtin_amdgcn_global_load_lds((as1_void*)gsrc, (as3_void*)ldst,
                                             16, 0, 0);
        }
    };

    float acc[NOUT];
#pragma unroll
    for (int j = 0; j < NOUT; ++j) acc[j] = 0.f;

    stage(0, 0);
    __syncthreads();                 // implicit vmcnt(0): tile 0 resident

    for (int tile = 0; tile < NTILE; ++tile) {
        const int cur = tile & 1;
        if (tile + 1 < NTILE) stage(cur ^ 1, tile + 1);   // issue EARLY

        const int k0 = tile * KT;
        const float* r0 = &xt[cur][t * KT];
#pragma unroll
        for (int q = 0; q < 3; ++q) {
            float4 a = *(const float4*)(r0 + 4 * q);      // ds_read_b128
            const float* wr = W + (k0 + 4 * q) * NOUT;    // uniform -> s_load
#pragma unroll
            for (int j = 0; j < NOUT; ++j) {
                float w0 = wr[j];
                float w1 = wr[j + NOUT];
                float w2 = wr[j + 2 * NOUT];
                float w3 = wr[j + 3 * NOUT];
                acc[j] = fmaf(a.w, w3,
                         fmaf(a.z, w2,
                         fmaf(a.y, w1,
                         fmaf(a.x, w0, acc[j]))));
            }
        }
        __syncthreads();   // drains next-tile loads + guards buffer reuse
    }

    // transposed store: uh[b][j][row] with row = half*256+t -> lanes contiguous
    float* ub = uh + (size_t)b * NOUT * SEQ + half * RPB + t;
#pragma unroll
    for (int j = 0; j < NOUT; ++j) ub[(size_t)j * SEQ] = acc[j];
}

// ---------------- K2: dynamic routing (unchanged, ~46us) ----------------
__global__ __launch_bounds__(256) void route_kernel(
    const float* __restrict__ uh,  // [batch, 25, 512]
    float* __restrict__ out)       // [batch, 5, 5]
{
    const int b    = blockIdx.x;
    const int t    = threadIdx.x;
    const int lane = t & 63;
    const int wv   = t >> 6;

    __shared__ float red[4][NOUT];

    const float* ub = uh + (size_t)b * NOUT * SEQ;
    float u0[NOUT], u1[NOUT];
#pragma unroll
    for (int j = 0; j < NOUT; ++j) {
        u0[j] = ub[(size_t)j * SEQ + t];
        u1[j] = ub[(size_t)j * SEQ + t + 256];
    }

    float bb0[NCAP], bb1[NCAP];
#pragma unroll
    for (int c = 0; c < NCAP; ++c) { bb0[c] = 0.f; bb1[c] = 0.f; }

    float s[NOUT], sc[NCAP];

    for (int it = 0; it < ROUTINGS; ++it) {
        float m0 = bb0[0], m1 = bb1[0];
#pragma unroll
        for (int c = 1; c < NCAP; ++c) { m0 = fmaxf(m0, bb0[c]); m1 = fmaxf(m1, bb1[c]); }
        float e0[NCAP], e1[NCAP]; float se0 = 0.f, se1 = 0.f;
#pragma unroll
        for (int c = 0; c < NCAP; ++c) {
            e0[c] = __expf(bb0[c] - m0); se0 += e0[c];
            e1[c] = __expf(bb1[c] - m1); se1 += e1[c];
        }
        float i0 = 1.f / se0, i1 = 1.f / se1;

        float p[NOUT];
#pragma unroll
        for (int c = 0; c < NCAP; ++c) {
            float c0 = e0[c] * i0, c1 = e1[c] * i1;
#pragma unroll
            for (int k = 0; k < DCAP; ++k)
                p[c*DCAP + k] = fmaf(c0, u0[c*DCAP + k], c1 * u1[c*DCAP + k]);
        }

#pragma unroll
        for (int d = 1; d < 64; d <<= 1)
#pragma unroll
            for (int j = 0; j < NOUT; ++j) p[j] += __shfl_xor(p[j], d, 64);

        if (lane == 0) {
#pragma unroll
            for (int j = 0; j < NOUT; ++j) red[wv][j] = p[j];
        }
        __syncthreads();
#pragma unroll
        for (int j = 0; j < NOUT; ++j)
            s[j] = red[0][j] + red[1][j] + red[2][j] + red[3][j];
        __syncthreads();

#pragma unroll
        for (int c = 0; c < NCAP; ++c) {
            float ss = 0.f;
#pragma unroll
            for (int k = 0; k < DCAP; ++k)
                ss = fmaf(s[c*DCAP + k], s[c*DCAP + k], ss);
            sc[c] = rsqrtf(ss + 1e-7f);
        }

        if (it < ROUTINGS - 1) {
#pragma unroll
            for (int c = 0; c < NCAP; ++c) {
                float d0 = 0.f, d1 = 0.f;
#pragma unroll
                for (int k = 0; k < DCAP; ++k) {
                    float oc = s[c*DCAP + k] * sc[c];
                    d0 = fmaf(oc, u0[c*DCAP + k], d0);
                    d1 = fmaf(oc, u1[c*DCAP + k], d1);
                }
                bb0[c] = d0; bb1[c] = d1;
            }
        }
    }

    if (t < NOUT) out[(size_t)b * NOUT + t] = s[t] * sc[t / DCAP];
}

extern "C" void kernel_launch(void* const* d_in, const int* in_sizes, int n_in,
                              void* d_out, int out_size, void* d_ws, size_t ws_size,
                              hipStream_t stream) {
    const float* x   = (const float*)d_in[0];
    const float* W   = (const float*)d_in[1];
    float*       o   = (float*)d_out;
    float*       uh  = (float*)d_ws;                 // batch*25*512*4 = 52.4 MB
    const int batch  = in_sizes[0] / (SEQ * DIN);    // 1024

    gemm_kernel<<<dim3(batch * 2), dim3(256), 0, stream>>>(x, W, uh);
    route_kernel<<<dim3(batch),    dim3(256), 0, stream>>>(uh, o);
}